// Round 1
// baseline (77.174 us; speedup 1.0000x reference)
//
#include <hip/hip_runtime.h>
#include <math.h>

typedef short bf16x8 __attribute__((ext_vector_type(8)));
typedef float f32x4 __attribute__((ext_vector_type(4)));
typedef unsigned int uint32;

#define BETA 10.0f
#define THRESH -88.0f
// PER-ELEMENT 32-dim certificate fused into the MFMA (R11/R12-verified structure):
//   proxy = MFMA(x_bf16, 20*c_bf16, C=-10*||x_lo32||^2_fp32); bct = max(proxy) + (-10*||c_lo32||^2_fp32)
// With EXACT fp32 norms (new), the only error term is 20*(x_bf.c_bf - x.c)
// (bf16 dot rounding, |.| <~ 8 tail) — strictly TIGHTER than the old bf16-Gram
// version whose norm-rounding terms added to the slack budget. Skip when
// bct <= -88 => true arg64 <= -78 => contribution <= exp(-78)*1024*0.02 ~ 2e-32.
// Firing costs one per-ct cold block (16 cols x 128 rows, exact fp32, 64 dims).

// LDS map (88 KB -> 1 block/CU; centers staged ONCE per CU)
#define C_OFF    0        // 65536 B: centers lo-32-dim bf16 (x20), chunk layout
#define XB0_OFF  65536    // 8192 B: x tile 0 lo-half bf16 chunk layout
#define XB1_OFF  73728    // 8192 B: x tile 1
#define RED0_OFF 81920    // 1536 B: out accumulator tile 0 [128][3]
#define RED1_OFF 83456    // 1536 B: out accumulator tile 1 (contiguous with 0)
#define N2C_OFF  84992    // 4096 B: -10*||c_lo32||^2 fp32 [1024]
#define N2X0_OFF 89088    //  512 B: -10*||x_lo32||^2 fp32 [128] tile 0
#define N2X1_OFF 89600    //  512 B: tile 1
#define LDS_TOT  90112

__device__ __forceinline__ uint32 f2bf_rtne(float f) {
    uint32 u = __float_as_uint(f);
    u += 0x7FFFu + ((u >> 16) & 1u);
    return u >> 16;
}
__device__ __forceinline__ uint32 pk_rtne(float a, float b) {
    return f2bf_rtne(a) | (f2bf_rtne(b) << 16);
}
__device__ __forceinline__ f32x4 vmax4(f32x4 a, f32x4 b) {
    f32x4 r;
    r[0] = fmaxf(a[0], b[0]); r[1] = fmaxf(a[1], b[1]);
    r[2] = fmaxf(a[2], b[2]); r[3] = fmaxf(a[3], b[3]);
    return r;
}
#define MFMA __builtin_amdgcn_mfma_f32_16x16x32_bf16

// Persistent block = 256 rows x 1024 centers. Grid 256 = 1 block/CU.
// 1024 thr = 16 waves (4/SIMD, 2x the old latency hiding). Wave wv owns
// (tile t = wv>>3) x (col group cg = wv&7, 128 centers). x is read ONCE
// (exact-Wx pass also produces the bf16 staging + fp32 norm tables); the
// old per-wave Gram-MFMA + ds_bpermute chains for ||x||^2 / ||c||^2 are
// replaced by LDS table reads (f32x4 broadcast, conflict-free).
__global__ __launch_bounds__(1024, 4) void rbfn_fused(
    const float* __restrict__ x,
    const float* __restrict__ centers,
    const float* __restrict__ W,
    const float* __restrict__ bias,
    float* __restrict__ out)
{
    __shared__ __align__(16) char lds[LDS_TOT];

    const int tid = threadIdx.x;
    const int wv = tid >> 6;
    const int lane = tid & 63;
    const int quad = lane >> 4;
    const int l15 = lane & 15;
    const int row0 = blockIdx.x * 256;
    const int t  = wv >> 3;   // wave's row tile
    const int cg = wv & 7;    // wave's 128-col group

    // ---- stage centers lo-half, PRE-SCALED by 20 -> bf16 chunk layout,
    //      plus n2c[j] = -10*||c_j||^2_lo32 in fp32 (8 lanes per center) ----
    #pragma unroll
    for (int i = 0; i < 8; ++i) {
        const int f = i * 1024 + tid;
        const int j = f >> 3, sg = f & 7;
        const float4 v = *((const float4*)centers + j * 16 + sg);
        uint2 q;
        q.x = pk_rtne(20.f * v.x, 20.f * v.y);
        q.y = pk_rtne(20.f * v.z, 20.f * v.w);
        *(uint2*)(lds + C_OFF + (j >> 4) * 1024 + (sg >> 1) * 256 +
                  (j & 15) * 16 + (sg & 1) * 8) = q;
        float p = v.x * v.x + v.y * v.y + v.z * v.z + v.w * v.w;
        p += __shfl_xor(p, 1);
        p += __shfl_xor(p, 2);
        p += __shfl_xor(p, 4);
        if (sg == 0) *(float*)(lds + N2C_OFF + j * 4) = -BETA * p;
    }

    // ---- SINGLE x pass: exact fp32 x@Wx^T + bias -> red, lo-32 bf16 chunk
    //      staging, and n2x[r] = -10*||x_r||^2_lo32. Thread = (row, e),
    //      e in [0,4): floats [e*16, e*16+16) of its row. 256 rows/block. ----
    {
        const int row = tid >> 2, e = tid & 3;
        const int tt = row >> 7, rr = row & 127;
        const float4* xr = (const float4*)(x + (size_t)(row0 + row) * 64) + e * 4;
        const float4 a0 = xr[0], a1 = xr[1], a2 = xr[2], a3 = xr[3];
        const float4 av[4] = {a0, a1, a2, a3};

        if (e < 2) {   // lo-32 bf16 staging from already-loaded registers
            const int xb = tt ? XB1_OFF : XB0_OFF;
            #pragma unroll
            for (int i = 0; i < 4; ++i) {
                const int sg = e * 4 + i;
                uint2 q;
                q.x = pk_rtne(av[i].x, av[i].y);
                q.y = pk_rtne(av[i].z, av[i].w);
                *(uint2*)(lds + xb + (rr >> 4) * 1024 + (sg >> 1) * 256 +
                          (rr & 15) * 16 + (sg & 1) * 8) = q;
            }
        }
        float p = a0.x*a0.x + a0.y*a0.y + a0.z*a0.z + a0.w*a0.w
                + a1.x*a1.x + a1.y*a1.y + a1.z*a1.z + a1.w*a1.w
                + a2.x*a2.x + a2.y*a2.y + a2.z*a2.z + a2.w*a2.w
                + a3.x*a3.x + a3.y*a3.y + a3.z*a3.z + a3.w*a3.w;
        p += __shfl_xor(p, 1);   // e0+e1 = lo-32 sum (lanes e<2)
        if (e == 0)
            *(float*)(lds + (tt ? N2X1_OFF : N2X0_OFF) + rr * 4) = -BETA * p;

        float d0 = 0.f, d1 = 0.f, d2 = 0.f;
        #pragma unroll
        for (int i = 0; i < 4; ++i) {
            const float4 a = av[i];
            const float4 w0 = *((const float4*)(W + 0 * 1088) + e * 4 + i);
            const float4 w1 = *((const float4*)(W + 1 * 1088) + e * 4 + i);
            const float4 w2 = *((const float4*)(W + 2 * 1088) + e * 4 + i);
            d0 = fmaf(a.w, w0.w, fmaf(a.z, w0.z, fmaf(a.y, w0.y, fmaf(a.x, w0.x, d0))));
            d1 = fmaf(a.w, w1.w, fmaf(a.z, w1.z, fmaf(a.y, w1.y, fmaf(a.x, w1.x, d1))));
            d2 = fmaf(a.w, w2.w, fmaf(a.z, w2.z, fmaf(a.y, w2.y, fmaf(a.x, w2.x, d2))));
        }
        #pragma unroll
        for (int m = 1; m <= 2; m <<= 1) {
            d0 += __shfl_xor(d0, m);
            d1 += __shfl_xor(d1, m);
            d2 += __shfl_xor(d2, m);
        }
        if (e == 0) {
            float* red = (float*)(lds + (tt ? RED1_OFF : RED0_OFF));
            red[rr * 3 + 0] = d0 + bias[0];
            red[rr * 3 + 1] = d1 + bias[1];
            red[rr * 3 + 2] = d2 + bias[2];
        }
    }
    __syncthreads();   // barrier 1: all staging + tables + red seeds complete

    // ---- certificate: wave = tile t x cols [cg*128, cg*128+128) ----
    {
        const int xb = t ? XB1_OFF : XB0_OFF;
        const int nx = t ? N2X1_OFF : N2X0_OFF;
        float* red = (float*)(lds + (t ? RED1_OFF : RED0_OFF));

        bf16x8 af[8]; f32x4 prr[8];
        #pragma unroll
        for (int rt = 0; rt < 8; ++rt) {
            af[rt] = *(const bf16x8*)(lds + xb + rt * 1024 + quad * 256 + l15 * 16);
            // C layout row = quad*4+reg -> n2x[rt*16 + quad*4 + reg], broadcast read
            prr[rt] = *(const f32x4*)(lds + nx + rt * 64 + quad * 16);
        }
        float c2r[8];
        #pragma unroll
        for (int ct = 0; ct < 8; ++ct)
            c2r[ct] = *(const float*)(lds + N2C_OFF + (cg * 128 + ct * 16 + l15) * 4);

        #pragma unroll
        for (int ct = 0; ct < 8; ++ct) {
            const bf16x8 b = *(const bf16x8*)(lds + C_OFF + (cg * 8 + ct) * 1024 +
                                              quad * 256 + l15 * 16);
            f32x4 mx = {-1e30f, -1e30f, -1e30f, -1e30f};
            #pragma unroll
            for (int rt = 0; rt < 8; ++rt)
                mx = vmax4(mx, MFMA(af[rt], b, prr[rt], 0, 0, 0));
            const float bct = fmaxf(fmaxf(mx[0], mx[1]), fmaxf(mx[2], mx[3])) + c2r[ct];

            if (__builtin_expect(__ballot(bct > THRESH) != 0ull, 0)) {
                // cold: exact fp32, this ct's 16 cols x this tile's 128 rows
                const int j = cg * 128 + ct * 16 + l15;
                const float w0 = W[0 * 1088 + 64 + j];
                const float w1 = W[1 * 1088 + 64 + j];
                const float w2 = W[2 * 1088 + 64 + j];
                const float* cr = centers + (size_t)j * 64;
                #pragma clang loop unroll(disable)
                for (int rr2 = 0; rr2 < 32; ++rr2) {
                    const int r = quad * 32 + rr2;
                    const float* xr2 = x + (size_t)(row0 + t * 128 + r) * 64;
                    float dd = 0.f;
                    #pragma clang loop unroll(disable)
                    for (int k = 0; k < 64; ++k) {
                        const float df = xr2[k] - cr[k];
                        dd = fmaf(df, df, dd);
                    }
                    const float arg = -BETA * dd;
                    if (arg > -87.f) {
                        const float ee = expf(arg);
                        atomicAdd(&red[r * 3 + 0], ee * w0);
                        atomicAdd(&red[r * 3 + 1], ee * w1);
                        atomicAdd(&red[r * 3 + 2], ee * w2);
                    }
                }
            }
        }
    }
    __syncthreads();   // barrier 2: both red buffers final

    // ---- coalesced float4 stores (RED0|RED1 contiguous = 192 float4) ----
    if (tid < 192)
        ((float4*)out)[blockIdx.x * 192 + tid] =
            *((const float4*)(lds + RED0_OFF) + tid);
}

extern "C" void kernel_launch(void* const* d_in, const int* in_sizes, int n_in,
                              void* d_out, int out_size, void* d_ws, size_t ws_size,
                              hipStream_t stream) {
    const float* x       = (const float*)d_in[0];
    const float* centers = (const float*)d_in[1];
    const float* W       = (const float*)d_in[2];
    const float* b       = (const float*)d_in[3];
    float* out = (float*)d_out;

    const int n = in_sizes[0] / 64;   // 65536 rows
    rbfn_fused<<<n / 256, 1024, 0, stream>>>(x, centers, W, b, out);
}